// Round 8
// baseline (34.316 us; speedup 1.0000x reference)
//
#include <hip/hip_runtime.h>

// Scalar VQ (dim=1, K=64) via per-block bucket LUT, depth-1 LDS chain.
// key(x)=trunc(clamp(fmaf(x,inv,nlo),0,NB-1)) is fl-monotone; build uses the
// SAME key on the sorted codes, so for key(w)=k with <=2 codes in bucket k:
//   pos(w) = #{c<=w} = p0(k) + (S[p0+1]<=w) + (S[p0+2]<=w)   (exact)
// Candidates S[pos],S[pos+1] compared with exact reference arithmetic
// (d=fl(w-c), d2=fl(d*d)); >=3-code buckets NaN-marked; those and exact
// fl-ties between distinct values hit the verbatim naive first-index scan.
// R8: phase-batched hot loop — all 16 keys, then all 16 ds_read_b128 issued
// back-to-back (LDS latency overlapped), then all selects, then ONE __any
// guard per 16 elements (no per-element branch fence).

#define VQ_K 64
#define NB   1024
#define NW   (NB / 4)
#define TPB  1024
#define SEG  4
#define BLK_F4 (TPB * SEG)     // 4096 float4 = 16384 floats per block

__device__ __forceinline__ unsigned bytesum(unsigned x) {
    return (x + (x >> 8) + (x >> 16) + (x >> 24)) & 0xFFu;
}

__device__ __forceinline__ int vq_key(float x, float inv, float nlo) {
    float t = fmaf(x, inv, nlo);                      // monotone in x (inv>=0)
    t = fminf(fmaxf(t, 0.0f), (float)(NB - 1));       // v_med3_f32
    return (int)t;
}

__global__ __launch_bounds__(TPB, 8) void vq_kernel(
    const float* __restrict__ w,
    const float* __restrict__ cb,
    float* __restrict__ out,
    int n4)
{
    __shared__ float  C[VQ_K];        // original order (fallback)
    __shared__ float  S[VQ_K + 4];    // [0]=inf, [1..64] sorted, [65..67]=inf
    __shared__ float4 T[NB];          // 16 KB bucket table
    __shared__ unsigned H[NW];        // byte-packed counts
    __shared__ unsigned Hs[NW];       // word-exclusive code prefix

    const int tid = threadIdx.x;
    const float INF = __builtin_inff();
    const float NANF = __uint_as_float(0x7fc00000u);

    if (tid < VQ_K) C[tid] = cb[tid];
    if (tid < NW)   H[tid] = 0u;
    __syncthreads();

    // Stable rank-sort into S[1..64].
    if (tid < VQ_K) {
        const float c = C[tid];
        int rank = 0;
#pragma unroll
        for (int j = 0; j < VQ_K; ++j) {
            const float cj = C[j];
            rank += (cj < c || (cj == c && j < tid)) ? 1 : 0;
        }
        S[rank + 1] = c;
    }
    if (tid == 0) S[0] = INF;
    if (tid >= VQ_K + 1 && tid <= VQ_K + 3) S[tid] = INF;
    __syncthreads();

    const float lo  = S[1];
    const float hi  = S[VQ_K];
    const float inv = (hi > lo) ? ((float)NB / (hi - lo)) : 0.0f;
    const float nlo = -lo * inv;

    if (tid < VQ_K) {
        const int k = vq_key(S[tid + 1], inv, nlo);
        atomicAdd(&H[k >> 2], 1u << ((k & 3) * 8));
    }
    __syncthreads();

    // Wave 0: exclusive scan over 256 words.
    if (tid < 64) {
        const unsigned w0 = H[4 * tid], w1 = H[4 * tid + 1];
        const unsigned w2 = H[4 * tid + 2], w3 = H[4 * tid + 3];
        const int s0 = (int)bytesum(w0), s1 = (int)bytesum(w1);
        const int s2 = (int)bytesum(w2), s3 = (int)bytesum(w3);
        const int tot = s0 + s1 + s2 + s3;
        int acc = tot;
#pragma unroll
        for (int d = 1; d < 64; d <<= 1) {
            int u = __shfl_up(acc, d, 64);
            if (tid >= d) acc += u;
        }
        const int base = acc - tot;
        Hs[4 * tid]     = (unsigned)base;
        Hs[4 * tid + 1] = (unsigned)(base + s0);
        Hs[4 * tid + 2] = (unsigned)(base + s0 + s1);
        Hs[4 * tid + 3] = (unsigned)(base + s0 + s1 + s2);
    }
    __syncthreads();

    // Fill T (NB == TPB): lane-consecutive b128 writes, conflict-free.
    {
        const int b = tid;
        const unsigned hw = H[b >> 2];
        const int sh = (b & 3) * 8;
        const int h = (int)((hw >> sh) & 0xFFu);
        const unsigned below = hw & ((sh == 0) ? 0u : ((1u << sh) - 1u));
        const int p0 = (int)Hs[b >> 2] + (int)bytesum(below);
        float4 ent;
        if (h >= 3) ent = make_float4(NANF, NANF, NANF, NANF);
        else        ent = make_float4(S[p0], S[p0 + 1], S[p0 + 2], S[p0 + 3]);
        T[b] = ent;
    }
    __syncthreads();

    // ---- phase-batched stream: 16 elements per thread ----
    const int base4 = blockIdx.x * BLK_F4 + tid;
    const float4* in4 = reinterpret_cast<const float4*>(w);
    float4* out4 = reinterpret_cast<float4*>(out);

    // Phase 1: all global loads.
    float4 x[SEG];
#pragma unroll
    for (int s = 0; s < SEG; ++s) x[s] = in4[base4 + s * TPB];

    // Phase 2: all keys.
    int key[SEG][4];
#pragma unroll
    for (int s = 0; s < SEG; ++s) {
        const float* e = &x[s].x;
#pragma unroll
        for (int j = 0; j < 4; ++j) key[s][j] = vq_key(e[j], inv, nlo);
    }

    // Phase 3: all LDS reads issued back-to-back (latency overlap).
    float4 ent[SEG][4];
#pragma unroll
    for (int s = 0; s < SEG; ++s)
#pragma unroll
        for (int j = 0; j < 4; ++j) ent[s][j] = T[key[s][j]];

    // Phase 4: all selects/compares; collect bad-flags in a bitmask.
    float4 r[SEG];
    unsigned badmask = 0u;
#pragma unroll
    for (int s = 0; s < SEG; ++s) {
        const float* e = &x[s].x;
        float* ro = &r[s].x;
#pragma unroll
        for (int j = 0; j < 4; ++j) {
            const float wv = e[j];
            const float4 en = ent[s][j];
            const bool s1 = (en.y <= wv);
            const bool s2 = (en.z <= wv);
            const float cl = s2 ? en.z : (s1 ? en.y : en.x);
            const float cr = s2 ? en.w : (s1 ? en.z : en.y);
            const float dl = wv - cl, dr = wv - cr;
            const float dl2 = dl * dl, dr2 = dr * dr;
            const bool rlt = (dr2 < dl2);
            ro[j] = rlt ? cr : cl;
            const bool bad = !rlt && !(dl2 < dr2) && (cl != cr);
            badmask |= bad ? (1u << (s * 4 + j)) : 0u;
        }
    }

    // Phase 5: single guard for the whole batch (~never taken).
    if (__any(badmask != 0u)) {
        if (badmask != 0u) {
#pragma unroll
            for (int s = 0; s < SEG; ++s) {
                const float* e = &x[s].x;
                float* ro = &r[s].x;
#pragma unroll
                for (int j = 0; j < 4; ++j) {
                    if (badmask & (1u << (s * 4 + j))) {
                        const float wv = e[j];
                        float c0 = C[0], d0 = wv - c0;
                        float bd = d0 * d0, bv = c0;
#pragma unroll 1
                        for (int kk = 1; kk < VQ_K; ++kk) {
                            float cc = C[kk], d = wv - cc, dd = d * d;
                            bool lt = dd < bd;
                            bd = lt ? dd : bd;
                            bv = lt ? cc : bv;
                        }
                        ro[j] = bv;
                    }
                }
            }
        }
    }

    // Phase 6: all stores.
#pragma unroll
    for (int s = 0; s < SEG; ++s) out4[base4 + s * TPB] = r[s];
}

// Naive exact fallback for any remainder elements.
__global__ void vq_tail_kernel(const float* __restrict__ w,
                               const float* __restrict__ cb,
                               float* __restrict__ out, int start, int n) {
    int i = start + blockIdx.x * blockDim.x + threadIdx.x;
    if (i >= n) return;
    float wx = w[i];
    float c0 = cb[0], d0 = wx - c0;
    float bd = d0 * d0, bv = c0;
#pragma unroll
    for (int k = 1; k < VQ_K; ++k) {
        float c = cb[k], d = wx - c, dd = d * d;
        bool lt = dd < bd;
        bd = lt ? dd : bd;
        bv = lt ? c : bv;
    }
    out[i] = bv;
}

extern "C" void kernel_launch(void* const* d_in, const int* in_sizes, int n_in,
                              void* d_out, int out_size, void* d_ws, size_t ws_size,
                              hipStream_t stream) {
    const float* w  = (const float*)d_in[0];
    const float* cb = (const float*)d_in[1];
    float* out = (float*)d_out;
    const int n  = in_sizes[0];
    const int n4 = n / 4;

    const int grid = n4 / BLK_F4;                 // full blocks only
    if (grid > 0) {
        vq_kernel<<<grid, TPB, 0, stream>>>(w, cb, out, n4);
    }
    const int done = grid * BLK_F4 * 4;
    if (done < n) {
        const int rem = n - done;
        vq_tail_kernel<<<(rem + TPB - 1) / TPB, TPB, 0, stream>>>(w, cb, out, done, n);
    }
}

// Round 9
// 19.090 us; speedup vs baseline: 1.7976x; 1.7976x over previous
//
#include <hip/hip_runtime.h>

// Scalar VQ (dim=1, K=64) via per-block bucket LUT, depth-1 LDS chain.
// key(x)=trunc(clamp(fmaf(x,inv,nlo),0,NB-1)) is fl-monotone; build uses the
// SAME key on the sorted codes, so for key(w)=k with <=2 codes in bucket k:
//   pos(w) = #{c<=w} = p0(k) + (S[p0+1]<=w) + (S[p0+2]<=w)   (exact)
// Candidates S[pos],S[pos+1] compared with exact reference arithmetic
// (d=fl(w-c), d2=fl(d*d)); >=3-code buckets NaN-marked; those and exact
// fl-ties between distinct values hit the verbatim naive first-index scan.
// R9: R8's phase-batched hot path, sized to fit registers: SEG=2 (8 elems
// per batch, ~70 live VGPR), TPB=256, __launch_bounds__(256,4) (cap 128,
// no spill), 4 iters/block, grid=1024 (4 blocks/CU). One guard per batch.

#define VQ_K 64
#define NB   1024
#define NW   (NB / 4)
#define TPB  256
#define SEG  2                  // float4 per batch
#define ITERS 4                 // batches per block
#define BLK_F4 (TPB * SEG * ITERS)   // 2048 float4 = 8192 floats per block

__device__ __forceinline__ unsigned bytesum(unsigned x) {
    return (x + (x >> 8) + (x >> 16) + (x >> 24)) & 0xFFu;
}

__device__ __forceinline__ int vq_key(float x, float inv, float nlo) {
    float t = fmaf(x, inv, nlo);                      // monotone in x (inv>=0)
    t = fminf(fmaxf(t, 0.0f), (float)(NB - 1));       // v_med3_f32
    return (int)t;
}

__global__ __launch_bounds__(TPB, 4) void vq_kernel(
    const float* __restrict__ w,
    const float* __restrict__ cb,
    float* __restrict__ out,
    int n4)
{
    __shared__ float  C[VQ_K];        // original order (fallback)
    __shared__ float  S[VQ_K + 4];    // [0]=inf, [1..64] sorted, [65..67]=inf
    __shared__ float4 T[NB];          // 16 KB bucket table
    __shared__ unsigned H[NW];        // byte-packed counts
    __shared__ unsigned Hs[NW];       // word-exclusive code prefix

    const int tid = threadIdx.x;
    const float INF = __builtin_inff();
    const float NANF = __uint_as_float(0x7fc00000u);

    if (tid < VQ_K) C[tid] = cb[tid];
    H[tid] = 0u;                       // NW == TPB
    __syncthreads();

    // Stable rank-sort into S[1..64].
    if (tid < VQ_K) {
        const float c = C[tid];
        int rank = 0;
#pragma unroll
        for (int j = 0; j < VQ_K; ++j) {
            const float cj = C[j];
            rank += (cj < c || (cj == c && j < tid)) ? 1 : 0;
        }
        S[rank + 1] = c;
    }
    if (tid == 0) S[0] = INF;
    if (tid >= VQ_K + 1 && tid <= VQ_K + 3) S[tid] = INF;
    __syncthreads();

    const float lo  = S[1];
    const float hi  = S[VQ_K];
    const float inv = (hi > lo) ? ((float)NB / (hi - lo)) : 0.0f;
    const float nlo = -lo * inv;

    if (tid < VQ_K) {
        const int k = vq_key(S[tid + 1], inv, nlo);
        atomicAdd(&H[k >> 2], 1u << ((k & 3) * 8));
    }
    __syncthreads();

    // Wave 0: exclusive scan over 256 words.
    if (tid < 64) {
        const unsigned w0 = H[4 * tid], w1 = H[4 * tid + 1];
        const unsigned w2 = H[4 * tid + 2], w3 = H[4 * tid + 3];
        const int s0 = (int)bytesum(w0), s1 = (int)bytesum(w1);
        const int s2 = (int)bytesum(w2), s3 = (int)bytesum(w3);
        const int tot = s0 + s1 + s2 + s3;
        int acc = tot;
#pragma unroll
        for (int d = 1; d < 64; d <<= 1) {
            int u = __shfl_up(acc, d, 64);
            if (tid >= d) acc += u;
        }
        const int base = acc - tot;
        Hs[4 * tid]     = (unsigned)base;
        Hs[4 * tid + 1] = (unsigned)(base + s0);
        Hs[4 * tid + 2] = (unsigned)(base + s0 + s1);
        Hs[4 * tid + 3] = (unsigned)(base + s0 + s1 + s2);
    }
    __syncthreads();

    // Fill T: thread t owns buckets {t, 256+t, 512+t, 768+t} -> lane-consecutive
    // b128 writes, conflict-free.
#pragma unroll
    for (int j = 0; j < 4; ++j) {
        const int b = tid + j * TPB;
        const unsigned hw = H[b >> 2];
        const int sh = (b & 3) * 8;
        const int h = (int)((hw >> sh) & 0xFFu);
        const unsigned below = hw & ((sh == 0) ? 0u : ((1u << sh) - 1u));
        const int p0 = (int)Hs[b >> 2] + (int)bytesum(below);
        float4 ent;
        if (h >= 3) ent = make_float4(NANF, NANF, NANF, NANF);
        else        ent = make_float4(S[p0], S[p0 + 1], S[p0 + 2], S[p0 + 3]);
        T[b] = ent;
    }
    __syncthreads();

    // ---- phase-batched stream: ITERS batches of SEG float4 (8 elems) ----
    const float4* in4 = reinterpret_cast<const float4*>(w);
    float4* out4 = reinterpret_cast<float4*>(out);
    const int blk_base = blockIdx.x * BLK_F4;

#pragma unroll 1
    for (int it = 0; it < ITERS; ++it) {
        const int base4 = blk_base + it * (TPB * SEG) + tid;

        // Phase 1: loads.
        float4 x[SEG];
#pragma unroll
        for (int s = 0; s < SEG; ++s) x[s] = in4[base4 + s * TPB];

        // Phase 2: keys.
        int key[SEG][4];
#pragma unroll
        for (int s = 0; s < SEG; ++s) {
            const float* e = &x[s].x;
#pragma unroll
            for (int j = 0; j < 4; ++j) key[s][j] = vq_key(e[j], inv, nlo);
        }

        // Phase 3: LDS gathers issued back-to-back (latency overlap).
        float4 ent[SEG][4];
#pragma unroll
        for (int s = 0; s < SEG; ++s)
#pragma unroll
            for (int j = 0; j < 4; ++j) ent[s][j] = T[key[s][j]];

        // Phase 4: selects/compares; collect bad-flags.
        float4 r[SEG];
        unsigned badmask = 0u;
#pragma unroll
        for (int s = 0; s < SEG; ++s) {
            const float* e = &x[s].x;
            float* ro = &r[s].x;
#pragma unroll
            for (int j = 0; j < 4; ++j) {
                const float wv = e[j];
                const float4 en = ent[s][j];
                const bool s1 = (en.y <= wv);
                const bool s2 = (en.z <= wv);
                const float cl = s2 ? en.z : (s1 ? en.y : en.x);
                const float cr = s2 ? en.w : (s1 ? en.z : en.y);
                const float dl = wv - cl, dr = wv - cr;
                const float dl2 = dl * dl, dr2 = dr * dr;
                const bool rlt = (dr2 < dl2);
                ro[j] = rlt ? cr : cl;
                const bool bad = !rlt && !(dl2 < dr2) && (cl != cr);
                badmask |= bad ? (1u << (s * 4 + j)) : 0u;
            }
        }

        // Phase 5: one guard per batch (~never taken).
        if (__any(badmask != 0u)) {
            if (badmask != 0u) {
#pragma unroll
                for (int s = 0; s < SEG; ++s) {
                    const float* e = &x[s].x;
                    float* ro = &r[s].x;
#pragma unroll
                    for (int j = 0; j < 4; ++j) {
                        if (badmask & (1u << (s * 4 + j))) {
                            const float wv = e[j];
                            float c0 = C[0], d0 = wv - c0;
                            float bd = d0 * d0, bv = c0;
#pragma unroll 1
                            for (int kk = 1; kk < VQ_K; ++kk) {
                                float cc = C[kk], d = wv - cc, dd = d * d;
                                bool lt = dd < bd;
                                bd = lt ? dd : bd;
                                bv = lt ? cc : bv;
                            }
                            ro[j] = bv;
                        }
                    }
                }
            }
        }

        // Phase 6: stores.
#pragma unroll
        for (int s = 0; s < SEG; ++s) out4[base4 + s * TPB] = r[s];
    }
}

// Naive exact fallback for any remainder elements.
__global__ void vq_tail_kernel(const float* __restrict__ w,
                               const float* __restrict__ cb,
                               float* __restrict__ out, int start, int n) {
    int i = start + blockIdx.x * blockDim.x + threadIdx.x;
    if (i >= n) return;
    float wx = w[i];
    float c0 = cb[0], d0 = wx - c0;
    float bd = d0 * d0, bv = c0;
#pragma unroll
    for (int k = 1; k < VQ_K; ++k) {
        float c = cb[k], d = wx - c, dd = d * d;
        bool lt = dd < bd;
        bd = lt ? dd : bd;
        bv = lt ? c : bv;
    }
    out[i] = bv;
}

extern "C" void kernel_launch(void* const* d_in, const int* in_sizes, int n_in,
                              void* d_out, int out_size, void* d_ws, size_t ws_size,
                              hipStream_t stream) {
    const float* w  = (const float*)d_in[0];
    const float* cb = (const float*)d_in[1];
    float* out = (float*)d_out;
    const int n  = in_sizes[0];
    const int n4 = n / 4;

    const int grid = n4 / BLK_F4;                 // full blocks only
    if (grid > 0) {
        vq_kernel<<<grid, TPB, 0, stream>>>(w, cb, out, n4);
    }
    const int done = grid * BLK_F4 * 4;
    if (done < n) {
        const int rem = n - done;
        vq_tail_kernel<<<(rem + TPB - 1) / TPB, TPB, 0, stream>>>(w, cb, out, done, n);
    }
}

// Round 11
// 18.062 us; speedup vs baseline: 1.8999x; 1.0569x over previous
//
#include <hip/hip_runtime.h>

// Scalar VQ (dim=1, K=64) via per-block bucket LUT, depth-1 LDS chain.
// key(x)=trunc(clamp(fmaf(x,inv,nlo),0,NB-1)) is fl-monotone; build uses the
// SAME key on the sorted codes, so for key(w)=k with <=2 codes in bucket k:
//   pos(w) = #{c<=w} = p0(k) + (S[p0+1]<=w) + (S[p0+2]<=w)   (exact)
// Candidates S[pos],S[pos+1] compared with exact reference arithmetic
// (d=fl(w-c), d2=fl(d*d)); >=3-code buckets NaN-marked; those and exact
// fl-ties between distinct values hit the verbatim naive first-index scan.
// R11 = R10 with the nontemporal store fixed: use a native clang vector type
// (ext_vector_type(4)) — __builtin_nontemporal_store rejects HIP_vector_type.

#define VQ_K 64
#define NB   1024
#define NW   (NB / 4)
#define TPB  256
#define SEG  2                  // float4 per batch
#define ITERS 4                 // batches per block
#define BLK_F4 (TPB * SEG * ITERS)   // 2048 float4 = 8192 floats per block

typedef float f32x4n __attribute__((ext_vector_type(4)));   // native vec4

__device__ __forceinline__ unsigned bytesum(unsigned x) {
    return (x + (x >> 8) + (x >> 16) + (x >> 24)) & 0xFFu;
}

__device__ __forceinline__ int vq_key(float x, float inv, float nlo) {
    float t = fmaf(x, inv, nlo);                      // monotone in x (inv>=0)
    t = fminf(fmaxf(t, 0.0f), (float)(NB - 1));       // v_med3_f32
    return (int)t;
}

__global__ __launch_bounds__(TPB, 4) void vq_kernel(
    const float* __restrict__ w,
    const float* __restrict__ cb,
    float* __restrict__ out,
    int n4)
{
    __shared__ float  C[VQ_K];        // original order (fallback)
    __shared__ float  S[VQ_K + 4];    // [0]=inf, [1..64] sorted, [65..67]=inf
    __shared__ float4 T[NB];          // 16 KB bucket table
    __shared__ unsigned H[NW];        // byte-packed counts
    __shared__ unsigned Hs[NW];       // word-exclusive code prefix

    const int tid = threadIdx.x;
    const float INF = __builtin_inff();
    const float NANF = __uint_as_float(0x7fc00000u);

    if (tid < VQ_K) C[tid] = cb[tid];
    H[tid] = 0u;                       // NW == TPB
    __syncthreads();

    // Stable rank-sort into S[1..64].
    if (tid < VQ_K) {
        const float c = C[tid];
        int rank = 0;
#pragma unroll
        for (int j = 0; j < VQ_K; ++j) {
            const float cj = C[j];
            rank += (cj < c || (cj == c && j < tid)) ? 1 : 0;
        }
        S[rank + 1] = c;
    }
    if (tid == 0) S[0] = INF;
    if (tid >= VQ_K + 1 && tid <= VQ_K + 3) S[tid] = INF;
    __syncthreads();

    const float lo  = S[1];
    const float hi  = S[VQ_K];
    const float inv = (hi > lo) ? ((float)NB / (hi - lo)) : 0.0f;
    const float nlo = -lo * inv;

    if (tid < VQ_K) {
        const int k = vq_key(S[tid + 1], inv, nlo);
        atomicAdd(&H[k >> 2], 1u << ((k & 3) * 8));
    }
    __syncthreads();

    // Wave 0: exclusive scan over 256 words.
    if (tid < 64) {
        const unsigned w0 = H[4 * tid], w1 = H[4 * tid + 1];
        const unsigned w2 = H[4 * tid + 2], w3 = H[4 * tid + 3];
        const int s0 = (int)bytesum(w0), s1 = (int)bytesum(w1);
        const int s2 = (int)bytesum(w2), s3 = (int)bytesum(w3);
        const int tot = s0 + s1 + s2 + s3;
        int acc = tot;
#pragma unroll
        for (int d = 1; d < 64; d <<= 1) {
            int u = __shfl_up(acc, d, 64);
            if (tid >= d) acc += u;
        }
        const int base = acc - tot;
        Hs[4 * tid]     = (unsigned)base;
        Hs[4 * tid + 1] = (unsigned)(base + s0);
        Hs[4 * tid + 2] = (unsigned)(base + s0 + s1);
        Hs[4 * tid + 3] = (unsigned)(base + s0 + s1 + s2);
    }
    __syncthreads();

    // Fill T: thread t owns buckets {t, 256+t, 512+t, 768+t} -> lane-consecutive
    // b128 writes, conflict-free.
#pragma unroll
    for (int j = 0; j < 4; ++j) {
        const int b = tid + j * TPB;
        const unsigned hw = H[b >> 2];
        const int sh = (b & 3) * 8;
        const int h = (int)((hw >> sh) & 0xFFu);
        const unsigned below = hw & ((sh == 0) ? 0u : ((1u << sh) - 1u));
        const int p0 = (int)Hs[b >> 2] + (int)bytesum(below);
        float4 ent;
        if (h >= 3) ent = make_float4(NANF, NANF, NANF, NANF);
        else        ent = make_float4(S[p0], S[p0 + 1], S[p0 + 2], S[p0 + 3]);
        T[b] = ent;
    }
    __syncthreads();

    // ---- phase-batched stream with cross-iteration load prefetch ----
    const float4* in4 = reinterpret_cast<const float4*>(w);
    f32x4n* out4 = reinterpret_cast<f32x4n*>(out);
    const int blk_base = blockIdx.x * BLK_F4;

    float4 x[SEG];
#pragma unroll
    for (int s = 0; s < SEG; ++s) x[s] = in4[blk_base + tid + s * TPB];

#pragma unroll 1
    for (int it = 0; it < ITERS; ++it) {
        const int base4 = blk_base + it * (TPB * SEG) + tid;

        // Prefetch next iteration's inputs (independent of this iteration).
        float4 xn[SEG];
        if (it + 1 < ITERS) {
#pragma unroll
            for (int s = 0; s < SEG; ++s)
                xn[s] = in4[base4 + (TPB * SEG) + s * TPB];
        }

        // Keys.
        int key[SEG][4];
#pragma unroll
        for (int s = 0; s < SEG; ++s) {
            const float* e = &x[s].x;
#pragma unroll
            for (int j = 0; j < 4; ++j) key[s][j] = vq_key(e[j], inv, nlo);
        }

        // LDS gathers issued back-to-back (latency overlap).
        float4 ent[SEG][4];
#pragma unroll
        for (int s = 0; s < SEG; ++s)
#pragma unroll
            for (int j = 0; j < 4; ++j) ent[s][j] = T[key[s][j]];

        // Selects/compares; collect bad-flags.
        float4 r[SEG];
        unsigned badmask = 0u;
#pragma unroll
        for (int s = 0; s < SEG; ++s) {
            const float* e = &x[s].x;
            float* ro = &r[s].x;
#pragma unroll
            for (int j = 0; j < 4; ++j) {
                const float wv = e[j];
                const float4 en = ent[s][j];
                const bool s1 = (en.y <= wv);
                const bool s2 = (en.z <= wv);
                const float cl = s2 ? en.z : (s1 ? en.y : en.x);
                const float cr = s2 ? en.w : (s1 ? en.z : en.y);
                const float dl = wv - cl, dr = wv - cr;
                const float dl2 = dl * dl, dr2 = dr * dr;
                const bool rlt = (dr2 < dl2);
                ro[j] = rlt ? cr : cl;
                const bool bad = !rlt && !(dl2 < dr2) && (cl != cr);
                badmask |= bad ? (1u << (s * 4 + j)) : 0u;
            }
        }

        // One guard per batch (~never taken).
        if (__any(badmask != 0u)) {
            if (badmask != 0u) {
#pragma unroll
                for (int s = 0; s < SEG; ++s) {
                    const float* e = &x[s].x;
                    float* ro = &r[s].x;
#pragma unroll
                    for (int j = 0; j < 4; ++j) {
                        if (badmask & (1u << (s * 4 + j))) {
                            const float wv = e[j];
                            float c0 = C[0], d0 = wv - c0;
                            float bd = d0 * d0, bv = c0;
#pragma unroll 1
                            for (int kk = 1; kk < VQ_K; ++kk) {
                                float cc = C[kk], d = wv - cc, dd = d * d;
                                bool lt = dd < bd;
                                bd = lt ? dd : bd;
                                bv = lt ? cc : bv;
                            }
                            ro[j] = bv;
                        }
                    }
                }
            }
        }

        // Nontemporal streaming stores (native vector type).
#pragma unroll
        for (int s = 0; s < SEG; ++s) {
            f32x4n rv;
            rv.x = r[s].x; rv.y = r[s].y; rv.z = r[s].z; rv.w = r[s].w;
            __builtin_nontemporal_store(rv, &out4[base4 + s * TPB]);
        }

#pragma unroll
        for (int s = 0; s < SEG; ++s) x[s] = xn[s];
    }
}

// Naive exact fallback for any remainder elements.
__global__ void vq_tail_kernel(const float* __restrict__ w,
                               const float* __restrict__ cb,
                               float* __restrict__ out, int start, int n) {
    int i = start + blockIdx.x * blockDim.x + threadIdx.x;
    if (i >= n) return;
    float wx = w[i];
    float c0 = cb[0], d0 = wx - c0;
    float bd = d0 * d0, bv = c0;
#pragma unroll
    for (int k = 1; k < VQ_K; ++k) {
        float c = cb[k], d = wx - c, dd = d * d;
        bool lt = dd < bd;
        bd = lt ? dd : bd;
        bv = lt ? c : bv;
    }
    out[i] = bv;
}

extern "C" void kernel_launch(void* const* d_in, const int* in_sizes, int n_in,
                              void* d_out, int out_size, void* d_ws, size_t ws_size,
                              hipStream_t stream) {
    const float* w  = (const float*)d_in[0];
    const float* cb = (const float*)d_in[1];
    float* out = (float*)d_out;
    const int n  = in_sizes[0];
    const int n4 = n / 4;

    const int grid = n4 / BLK_F4;                 // full blocks only
    if (grid > 0) {
        vq_kernel<<<grid, TPB, 0, stream>>>(w, cb, out, n4);
    }
    const int done = grid * BLK_F4 * 4;
    if (done < n) {
        const int rem = n - done;
        vq_tail_kernel<<<(rem + TPB - 1) / TPB, TPB, 0, stream>>>(w, cb, out, done, n);
    }
}